// Round 1
// baseline (289.685 us; speedup 1.0000x reference)
//
#include <hip/hip_runtime.h>
#include <math.h>

// ---------------------------------------------------------------------------
// JAX threefry2x32 (exact port) + dropout mask replication.
// PARTITIONABLE=1 matches jax_threefry_partitionable=True (default jax>=0.4.36)
// ---------------------------------------------------------------------------
#define PARTITIONABLE 1

__device__ __forceinline__ void threefry2x32(unsigned k0, unsigned k1,
                                             unsigned c0, unsigned c1,
                                             unsigned &o0, unsigned &o1) {
  unsigned ks2 = k0 ^ k1 ^ 0x1BD11BDAu;
  unsigned x0 = c0 + k0, x1 = c1 + k1;
#define ROTL(v, n) (((v) << (n)) | ((v) >> (32 - (n))))
#define R4(a, b, c, d)                                   \
  { x0 += x1; x1 = ROTL(x1, a); x1 ^= x0;                \
    x0 += x1; x1 = ROTL(x1, b); x1 ^= x0;                \
    x0 += x1; x1 = ROTL(x1, c); x1 ^= x0;                \
    x0 += x1; x1 = ROTL(x1, d); x1 ^= x0; }
  R4(13, 15, 26, 6);  x0 += k1;  x1 += ks2 + 1u;
  R4(17, 29, 16, 24); x0 += ks2; x1 += k0 + 2u;
  R4(13, 15, 26, 6);  x0 += k0;  x1 += k1 + 3u;
  R4(17, 29, 16, 24); x0 += k1;  x1 += ks2 + 4u;
  R4(13, 15, 26, 6);  x0 += ks2; x1 += k0 + 5u;
  o0 = x0; o1 = x1;
#undef R4
#undef ROTL
}

// dropout keep-scale for element flat index i of a (128,256) mask,
// layer 0 -> dk1, layer 1 -> dk2 of split(key(7)). Returns 0 or 2 (=1/(1-p)).
__device__ __forceinline__ float dropout_scale(int layer, unsigned i) {
#if PARTITIONABLE
  unsigned d0, d1, y0, y1;
  threefry2x32(0u, 7u, 0u, (unsigned)layer, d0, d1);   // fold-like split
  threefry2x32(d0, d1, 0u, i, y0, y1);                 // counter (0, i)
  unsigned bits = y0 ^ y1;                             // 32-bit partitionable
#else
  unsigned a0, b0, a1, b1v, y0, y1;
  threefry2x32(0u, 7u, 0u, 2u, a0, b0);                // original split
  threefry2x32(0u, 7u, 1u, 3u, a1, b1v);
  unsigned k0 = (layer == 0) ? a0 : b0;
  unsigned k1 = (layer == 0) ? a1 : b1v;
  const unsigned half = 16384u;                        // 128*256/2
  unsigned lane = (i < half) ? 0u : 1u;
  unsigned j = lane ? (i - half) : i;
  threefry2x32(k0, k1, j, j + half, y0, y1);
  unsigned bits = lane ? y1 : y0;
#endif
  // uniform = bitcast((bits>>9)|0x3f800000)-1 < 0.5  <=>  bit31 == 0
  return (bits & 0x80000000u) ? 0.0f : 2.0f;
}

__device__ __forceinline__ float sigmoidf(float x) {
  return 1.0f / (1.0f + expf(-x));
}

// ---------------------------------------------------------------------------
// 1) Prenet: x = drop(relu(mels@W1+b1)); x = drop(relu(x@W2+b2)); q = x@Wq
//    Writes x into rnn_in[:, 0:256] and q into q_ws.
// ---------------------------------------------------------------------------
__global__ __launch_bounds__(256) void prenet_kernel(
    const float* __restrict__ mels, const float* __restrict__ W1,
    const float* __restrict__ b1, const float* __restrict__ W2,
    const float* __restrict__ b2, const float* __restrict__ Wq,
    float* __restrict__ rnn_in, float* __restrict__ q_out) {
  int b = blockIdx.x;
  int j = threadIdx.x;
  __shared__ float mel_s[80];
  __shared__ float x1_s[256];
  __shared__ float x2_s[256];
  if (j < 80) mel_s[j] = mels[b * 80 + j];
  __syncthreads();
  float s = b1[j];
  for (int m = 0; m < 80; ++m) s = fmaf(mel_s[m], W1[m * 256 + j], s);
  s = fmaxf(s, 0.0f) * dropout_scale(0, (unsigned)(b * 256 + j));
  x1_s[j] = s;
  __syncthreads();
  float s2 = b2[j];
  for (int m = 0; m < 256; ++m) s2 = fmaf(x1_s[m], W2[m * 256 + j], s2);
  s2 = fmaxf(s2, 0.0f) * dropout_scale(1, (unsigned)(b * 256 + j));
  x2_s[j] = s2;
  rnn_in[(size_t)b * 768 + j] = s2;
  __syncthreads();
  if (j < 128) {
    float sq = 0.0f;
    for (int m = 0; m < 256; ++m) sq = fmaf(x2_s[m], Wq[m * 128 + j], sq);
    q_out[b * 128 + j] = sq;
  }
}

// ---------------------------------------------------------------------------
// 2) score[b,t] = sum_a tanh(q[b,a]+bk[a]+ (enc[b,t,:]@Wk)[a]) * va[a] + bsc
//    Block: 32 t-rows x 128 a-cols, K=512. 4x4 register tile per thread.
// ---------------------------------------------------------------------------
__global__ __launch_bounds__(256) void score_kernel(
    const float* __restrict__ enc, const float* __restrict__ Wk,
    const float* __restrict__ bk, const float* __restrict__ q,
    const float* __restrict__ va_g, const float* __restrict__ bscore,
    float* __restrict__ score) {
  int b = blockIdx.y;
  int t0 = blockIdx.x * 32;
  int tid = threadIdx.x;
  __shared__ float E[64][36];    // k-major enc tile, 32 rows
  __shared__ float Ws[64][132];  // k-major Wk tile, 128 cols
  __shared__ float qv[128];
  __shared__ float red[32][33];
  if (tid < 128) qv[tid] = q[b * 128 + tid] + bk[tid];
  float acc[4][4] = {};
  int rg = tid >> 5;   // 0..7  -> rows rg*4..rg*4+3
  int cg = tid & 31;   // 0..31 -> cols cg*4..cg*4+3
  for (int k0 = 0; k0 < 512; k0 += 64) {
    __syncthreads();
    {  // stage enc: 32 rows x 64 k, transpose to k-major
      int kk4 = (tid & 15) * 4;
      int r = tid >> 4;  // 0..15
      for (int pp = 0; pp < 2; ++pp) {
        int rr = r + pp * 16;
        const float4 v = *reinterpret_cast<const float4*>(
            &enc[((size_t)(b * 512 + t0 + rr)) * 512 + k0 + kk4]);
        E[kk4 + 0][rr] = v.x; E[kk4 + 1][rr] = v.y;
        E[kk4 + 2][rr] = v.z; E[kk4 + 3][rr] = v.w;
      }
    }
    {  // stage Wk: 64 k x 128 a (already k-major)
      int a4 = (tid & 31) * 4;
      int kk = tid >> 5;  // 0..7
      for (int pp = 0; pp < 8; ++pp) {
        int kkk = kk + pp * 8;
        *reinterpret_cast<float4*>(&Ws[kkk][a4]) =
            *reinterpret_cast<const float4*>(&Wk[(size_t)(k0 + kkk) * 128 + a4]);
      }
    }
    __syncthreads();
    for (int kk = 0; kk < 64; ++kk) {
      float4 e = *reinterpret_cast<const float4*>(&E[kk][rg * 4]);
      float4 w = *reinterpret_cast<const float4*>(&Ws[kk][cg * 4]);
      float ee[4] = {e.x, e.y, e.z, e.w};
      float ww[4] = {w.x, w.y, w.z, w.w};
      for (int r = 0; r < 4; ++r)
        for (int c = 0; c < 4; ++c)
          acc[r][c] = fmaf(ee[r], ww[c], acc[r][c]);
    }
  }
  float vav[4], qvv[4];
  for (int c = 0; c < 4; ++c) {
    int a = cg * 4 + c;
    vav[c] = va_g[a];
    qvv[c] = qv[a];
  }
  float part[4];
  for (int r = 0; r < 4; ++r) {
    float sr = 0.0f;
    for (int c = 0; c < 4; ++c) sr += tanhf(qvv[c] + acc[r][c]) * vav[c];
    part[r] = sr;
  }
  __syncthreads();
  for (int r = 0; r < 4; ++r) red[rg * 4 + r][cg] = part[r];
  __syncthreads();
  if (tid < 32) {
    float sr = bscore[0];
    for (int g = 0; g < 32; ++g) sr += red[tid][g];
    score[b * 512 + t0 + tid] = sr;
  }
}

// ---------------------------------------------------------------------------
// 3) Monotonic-attention scan per batch row (T=512).
// ---------------------------------------------------------------------------
__global__ __launch_bounds__(512) void scan_kernel(
    const float* __restrict__ score, const float* __restrict__ prev_align,
    float* __restrict__ align_out) {
  int b = blockIdx.x, t = threadIdx.x;
  __shared__ float s[512];
  float p = sigmoidf(score[b * 512 + t]);
  float omp = 1.0f - p;
  s[t] = omp;
  __syncthreads();
  for (int off = 1; off < 512; off <<= 1) {  // inclusive cumprod
    float v = (t >= off) ? s[t - off] : 1.0f;
    __syncthreads();
    if (t >= off) s[t] *= v;
    __syncthreads();
  }
  float cp_excl = (t == 0) ? 1.0f : s[t - 1];
  __syncthreads();
  float denom = fminf(fmaxf(cp_excl, 1e-10f), 1.0f);
  float r = prev_align[b * 512 + t] / denom;
  s[t] = r;
  __syncthreads();
  for (int off = 1; off < 512; off <<= 1) {  // inclusive cumsum
    float v = (t >= off) ? s[t - off] : 0.0f;
    __syncthreads();
    if (t >= off) s[t] += v;
    __syncthreads();
  }
  align_out[b * 512 + t] = p * cp_excl * s[t];
}

// ---------------------------------------------------------------------------
// 4) attentions partials: ap[tc][b][v] = sum_{t in chunk} align*enc
//    Skips loads for align==0 (uniform branch; cumprod underflow makes most 0)
// ---------------------------------------------------------------------------
__global__ __launch_bounds__(256) void att_part_kernel(
    const float* __restrict__ align, const float* __restrict__ enc,
    float* __restrict__ ap) {
  int tc = blockIdx.x;  // 0..7
  int vt = blockIdx.y;  // 0..1
  int b = blockIdx.z;   // 0..127
  int tid = threadIdx.x;
  int v = vt * 256 + tid;
  __shared__ float al[64];
  if (tid < 64) al[tid] = align[b * 512 + tc * 64 + tid];
  __syncthreads();
  float acc = 0.0f;
  for (int tt = 0; tt < 64; ++tt) {
    float a = al[tt];
    if (a != 0.0f)
      acc = fmaf(a, enc[((size_t)(b * 512 + tc * 64 + tt)) * 512 + v], acc);
  }
  ap[((size_t)tc * 128 + b) * 512 + v] = acc;
}

__global__ __launch_bounds__(256) void att_comb_kernel(
    const float* __restrict__ ap, float* __restrict__ rnn_in,
    float* __restrict__ proj_in) {
  int b = blockIdx.x;
  int v = blockIdx.y * 256 + threadIdx.x;
  float s = 0.0f;
  for (int tc = 0; tc < 8; ++tc) s += ap[((size_t)tc * 128 + b) * 512 + v];
  rnn_in[(size_t)b * 768 + 256 + v] = s;
  proj_in[(size_t)b * 1536 + 1024 + v] = s;
}

// ---------------------------------------------------------------------------
// 5) LSTM z partials: parts[zp] = A_seg[krange] @ W_seg[krange]
//    Block: 64 rows x 64 cols, 4x4 tile/thread. zp: {seg0 k-half0/1, seg1 ...}
// ---------------------------------------------------------------------------
__global__ __launch_bounds__(256) void zgemm_kernel(
    const float* __restrict__ A0, int K0, const float* __restrict__ W0,
    const float* __restrict__ A1, int K1, const float* __restrict__ W1,
    float* __restrict__ parts) {
  int cb = blockIdx.x;  // 64 col-blocks of 64
  int rb = blockIdx.y;  // 2 row-blocks of 64
  int zp = blockIdx.z;  // 0..3
  int seg = zp >> 1, kh = zp & 1;
  const float* A = seg ? A1 : A0;
  const float* W = seg ? W1 : W0;
  int K = seg ? K1 : K0;
  int kbeg = kh * (K >> 1), kend = kbeg + (K >> 1);
  int c0 = cb * 64, r0 = rb * 64;
  int tid = threadIdx.x;
  int cg = tid & 15, rg = tid >> 4;  // 16x16 thread grid
  __shared__ float As[32][68];
  __shared__ float Bs[32][68];
  float acc[4][4] = {};
  for (int k0 = kbeg; k0 < kend; k0 += 32) {
    __syncthreads();
    {  // stage A: 64 rows x 32 k -> k-major
      int kk4 = (tid & 7) * 4;
      int r = tid >> 3;  // 0..31
      for (int pp = 0; pp < 2; ++pp) {
        int rr = r + pp * 32;
        float4 v = *reinterpret_cast<const float4*>(
            &A[(size_t)(r0 + rr) * K + k0 + kk4]);
        As[kk4 + 0][rr] = v.x; As[kk4 + 1][rr] = v.y;
        As[kk4 + 2][rr] = v.z; As[kk4 + 3][rr] = v.w;
      }
      // stage W: 32 k x 64 cols
      int c4 = (tid & 15) * 4;
      int kk = tid >> 4;  // 0..15
      for (int pp = 0; pp < 2; ++pp) {
        int kkk = kk + pp * 16;
        *reinterpret_cast<float4*>(&Bs[kkk][c4]) =
            *reinterpret_cast<const float4*>(&W[(size_t)(k0 + kkk) * 4096 + c0 + c4]);
      }
    }
    __syncthreads();
    for (int kk = 0; kk < 32; ++kk) {
      float4 a = *reinterpret_cast<const float4*>(&As[kk][rg * 4]);
      float4 w = *reinterpret_cast<const float4*>(&Bs[kk][cg * 4]);
      float aa[4] = {a.x, a.y, a.z, a.w};
      float ww[4] = {w.x, w.y, w.z, w.w};
      for (int r = 0; r < 4; ++r)
        for (int c = 0; c < 4; ++c)
          acc[r][c] = fmaf(aa[r], ww[c], acc[r][c]);
    }
  }
  float* outp = parts + (size_t)zp * (128 * 4096);
  for (int r = 0; r < 4; ++r) {
    float4 v = {acc[r][0], acc[r][1], acc[r][2], acc[r][3]};
    *reinterpret_cast<float4*>(&outp[(size_t)(r0 + rg * 4 + r) * 4096 + c0 + cg * 4]) = v;
  }
}

// ---------------------------------------------------------------------------
// 6) LSTM gates: z = sum(parts)+bias; h,c update. Optionally copy h into dst2.
// ---------------------------------------------------------------------------
__global__ __launch_bounds__(256) void gate_kernel(
    const float* __restrict__ parts, const float* __restrict__ bias,
    const float* __restrict__ c_prev, float* __restrict__ h_out,
    float* __restrict__ c_out, float* __restrict__ h_dst2, int ld2) {
  int idx = blockIdx.x * 256 + threadIdx.x;  // 0..131071
  int b = idx >> 10, j = idx & 1023;
  float zv[4];
  for (int g = 0; g < 4; ++g) {
    size_t off = (size_t)b * 4096 + g * 1024 + j;
    float s = bias[g * 1024 + j];
    for (int p = 0; p < 4; ++p) s += parts[(size_t)p * (128 * 4096) + off];
    zv[g] = s;
  }
  float ig = sigmoidf(zv[0]);
  float fg = sigmoidf(zv[1]);
  float gg = tanhf(zv[2]);
  float og = sigmoidf(zv[3]);
  float cn = fg * c_prev[idx] + ig * gg;
  float hn = og * tanhf(cn);
  h_out[idx] = hn;
  c_out[idx] = cn;
  if (h_dst2) h_dst2[(size_t)b * ld2 + j] = hn;
}

// ---------------------------------------------------------------------------
// 7) Projection: proj = proj_in @ W_proj + b_proj -> mel (80), stops (1)
// ---------------------------------------------------------------------------
__global__ __launch_bounds__(256) void proj_kernel(
    const float* __restrict__ proj_in, const float* __restrict__ Wp,
    const float* __restrict__ bp, float* __restrict__ mel,
    float* __restrict__ stops) {
  int b = blockIdx.x;
  int tid = threadIdx.x;
  __shared__ float row[1536];
  for (int i = tid; i < 1536; i += 256) row[i] = proj_in[(size_t)b * 1536 + i];
  __syncthreads();
  if (tid < 81) {
    float s = bp[tid];
    for (int m = 0; m < 1536; ++m) s = fmaf(row[m], Wp[m * 81 + tid], s);
    if (tid < 80) mel[b * 80 + tid] = s;
    else stops[b] = s;
  }
}

// ---------------------------------------------------------------------------
extern "C" void kernel_launch(void* const* d_in, const int* in_sizes, int n_in,
                              void* d_out, int out_size, void* d_ws,
                              size_t ws_size, hipStream_t stream) {
  const float* enc  = (const float*)d_in[0];
  const float* mels = (const float*)d_in[1];
  const float* prev = (const float*)d_in[2];
  const float* h1   = (const float*)d_in[3];
  const float* c1   = (const float*)d_in[4];
  const float* h2   = (const float*)d_in[5];
  const float* c2   = (const float*)d_in[6];
  const float* Wp1  = (const float*)d_in[7];
  const float* bp1  = (const float*)d_in[8];
  const float* Wp2  = (const float*)d_in[9];
  const float* bp2  = (const float*)d_in[10];
  const float* Wq   = (const float*)d_in[11];
  const float* Wk   = (const float*)d_in[12];
  const float* bk   = (const float*)d_in[13];
  const float* va   = (const float*)d_in[14];
  const float* bsc  = (const float*)d_in[15];
  const float* Wx1  = (const float*)d_in[16];
  const float* Wh1  = (const float*)d_in[17];
  const float* bl1  = (const float*)d_in[18];
  const float* Wx2  = (const float*)d_in[19];
  const float* Wh2  = (const float*)d_in[20];
  const float* bl2  = (const float*)d_in[21];
  const float* Wpj  = (const float*)d_in[22];
  const float* bpj  = (const float*)d_in[23];

  float* out = (float*)d_out;
  float* mel    = out;            // 128*80
  float* stops  = out + 10240;    // 128
  float* aligno = out + 10368;    // 128*512
  float* h1n    = out + 75904;    // 128*1024
  float* c1n    = out + 206976;
  float* h2n    = out + 338048;
  float* c2n    = out + 469120;

  float* ws = (float*)d_ws;
  float* q_ws   = ws;              // 16384
  float* sc_ws  = ws + 16384;      // 65536
  float* rnn_in = ws + 81920;      // 128*768
  float* prj_in = ws + 180224;     // 128*1536
  float* parts  = ws + 376832;     // 4 * 128*4096
  float* ap_ws  = ws + 2473984;    // 8*128*512   (end: 2998272 floats = 12 MB)

  hipLaunchKernelGGL(prenet_kernel, dim3(128), dim3(256), 0, stream,
                     mels, Wp1, bp1, Wp2, bp2, Wq, rnn_in, q_ws);
  hipLaunchKernelGGL(score_kernel, dim3(16, 128), dim3(256), 0, stream,
                     enc, Wk, bk, q_ws, va, bsc, sc_ws);
  hipLaunchKernelGGL(scan_kernel, dim3(128), dim3(512), 0, stream,
                     sc_ws, prev, aligno);
  hipLaunchKernelGGL(att_part_kernel, dim3(8, 2, 128), dim3(256), 0, stream,
                     aligno, enc, ap_ws);
  hipLaunchKernelGGL(att_comb_kernel, dim3(128, 2), dim3(256), 0, stream,
                     ap_ws, rnn_in, prj_in);
  hipLaunchKernelGGL(zgemm_kernel, dim3(64, 2, 4), dim3(256), 0, stream,
                     rnn_in, 768, Wx1, h1, 1024, Wh1, parts);
  hipLaunchKernelGGL(gate_kernel, dim3(512), dim3(256), 0, stream,
                     parts, bl1, c1, h1n, c1n, (float*)nullptr, 0);
  hipLaunchKernelGGL(zgemm_kernel, dim3(64, 2, 4), dim3(256), 0, stream,
                     h1n, 1024, Wx2, h2, 1024, Wh2, parts);
  hipLaunchKernelGGL(gate_kernel, dim3(512), dim3(256), 0, stream,
                     parts, bl2, c2, h2n, c2n, prj_in, 1536);
  hipLaunchKernelGGL(proj_kernel, dim3(128), dim3(256), 0, stream,
                     prj_in, Wpj, bpj, mel, stops);
}

// Round 2
// 195.932 us; speedup vs baseline: 1.4785x; 1.4785x over previous
//
#include <hip/hip_runtime.h>
#include <math.h>

typedef float f32x4 __attribute__((ext_vector_type(4)));
typedef __bf16 bf16x8 __attribute__((ext_vector_type(8)));
typedef __bf16 bf16x4 __attribute__((ext_vector_type(4)));

// ---------------------------------------------------------------------------
// JAX threefry2x32 (exact port) + dropout mask replication.
// ---------------------------------------------------------------------------
#define PARTITIONABLE 1

__device__ __forceinline__ void threefry2x32(unsigned k0, unsigned k1,
                                             unsigned c0, unsigned c1,
                                             unsigned &o0, unsigned &o1) {
  unsigned ks2 = k0 ^ k1 ^ 0x1BD11BDAu;
  unsigned x0 = c0 + k0, x1 = c1 + k1;
#define ROTL(v, n) (((v) << (n)) | ((v) >> (32 - (n))))
#define R4(a, b, c, d)                                   \
  { x0 += x1; x1 = ROTL(x1, a); x1 ^= x0;                \
    x0 += x1; x1 = ROTL(x1, b); x1 ^= x0;                \
    x0 += x1; x1 = ROTL(x1, c); x1 ^= x0;                \
    x0 += x1; x1 = ROTL(x1, d); x1 ^= x0; }
  R4(13, 15, 26, 6);  x0 += k1;  x1 += ks2 + 1u;
  R4(17, 29, 16, 24); x0 += ks2; x1 += k0 + 2u;
  R4(13, 15, 26, 6);  x0 += k0;  x1 += k1 + 3u;
  R4(17, 29, 16, 24); x0 += k1;  x1 += ks2 + 4u;
  R4(13, 15, 26, 6);  x0 += ks2; x1 += k0 + 5u;
  o0 = x0; o1 = x1;
#undef R4
#undef ROTL
}

__device__ __forceinline__ float dropout_scale(int layer, unsigned i) {
#if PARTITIONABLE
  unsigned d0, d1, y0, y1;
  threefry2x32(0u, 7u, 0u, (unsigned)layer, d0, d1);
  threefry2x32(d0, d1, 0u, i, y0, y1);
  unsigned bits = y0 ^ y1;
#else
  unsigned a0, b0, a1, b1v, y0, y1;
  threefry2x32(0u, 7u, 0u, 2u, a0, b0);
  threefry2x32(0u, 7u, 1u, 3u, a1, b1v);
  unsigned k0 = (layer == 0) ? a0 : b0;
  unsigned k1 = (layer == 0) ? a1 : b1v;
  const unsigned half = 16384u;
  unsigned lane = (i < half) ? 0u : 1u;
  unsigned j = lane ? (i - half) : i;
  threefry2x32(k0, k1, j, j + half, y0, y1);
  unsigned bits = lane ? y1 : y0;
#endif
  return (bits & 0x80000000u) ? 0.0f : 2.0f;
}

__device__ __forceinline__ float sigmoidf(float x) {
  return 1.0f / (1.0f + expf(-x));
}

// ---------------------------------------------------------------------------
// 1) Prenet
// ---------------------------------------------------------------------------
__global__ __launch_bounds__(256) void prenet_kernel(
    const float* __restrict__ mels, const float* __restrict__ W1,
    const float* __restrict__ b1, const float* __restrict__ W2,
    const float* __restrict__ b2, const float* __restrict__ Wq,
    float* __restrict__ rnn_in, float* __restrict__ q_out) {
  int b = blockIdx.x;
  int j = threadIdx.x;
  __shared__ float mel_s[80];
  __shared__ float x1_s[256];
  __shared__ float x2_s[256];
  if (j < 80) mel_s[j] = mels[b * 80 + j];
  __syncthreads();
  float s = b1[j];
  for (int m = 0; m < 80; ++m) s = fmaf(mel_s[m], W1[m * 256 + j], s);
  s = fmaxf(s, 0.0f) * dropout_scale(0, (unsigned)(b * 256 + j));
  x1_s[j] = s;
  __syncthreads();
  float s2 = b2[j];
  for (int m = 0; m < 256; ++m) s2 = fmaf(x1_s[m], W2[m * 256 + j], s2);
  s2 = fmaxf(s2, 0.0f) * dropout_scale(1, (unsigned)(b * 256 + j));
  x2_s[j] = s2;
  rnn_in[(size_t)b * 768 + j] = s2;
  __syncthreads();
  if (j < 128) {
    float sq = 0.0f;
    for (int m = 0; m < 256; ++m) sq = fmaf(x2_s[m], Wq[m * 128 + j], sq);
    q_out[b * 128 + j] = sq;
  }
}

// ---------------------------------------------------------------------------
// 1b) Wk -> WkT (transposed, bf16)
// ---------------------------------------------------------------------------
__global__ __launch_bounds__(256) void wkt_prep_kernel(
    const float* __restrict__ Wk, __bf16* __restrict__ WkT) {
  int gid = blockIdx.x * 256 + threadIdx.x;  // 0..16383
  int a = gid & 127;
  int k4 = (gid >> 7) * 4;
  bf16x4 w;
  for (int i = 0; i < 4; ++i) w[i] = (__bf16)Wk[(size_t)(k4 + i) * 128 + a];
  *reinterpret_cast<bf16x4*>(&WkT[(size_t)a * 512 + k4]) = w;
}

// ---------------------------------------------------------------------------
// 2) score via MFMA: z = enc(bf16) @ WkT(bf16); score = sum_a tanh(qv+z)*va
//    Block: 128t x 128a, 4 waves (2x2), each wave 64x64 = 4x4 frags 16x16x32.
//    LDS XOR-swizzle: elem ^= (row&7)<<3  (16B granularity at byte level).
// ---------------------------------------------------------------------------
__global__ __launch_bounds__(256) void score_mfma_kernel(
    const float* __restrict__ enc, const __bf16* __restrict__ WkT,
    const float* __restrict__ bk, const float* __restrict__ q,
    const float* __restrict__ va_g, const float* __restrict__ bscore,
    float* __restrict__ score) {
  int b = blockIdx.y;
  int t0 = blockIdx.x * 128;
  int tid = threadIdx.x;
  int lane = tid & 63, wid = tid >> 6;
  int wr = wid >> 1, wc = wid & 1;
  __shared__ __align__(16) __bf16 Eb[128 * 64];
  __shared__ __align__(16) __bf16 Wb[128 * 64];
  __shared__ float red[128][4];

  f32x4 acc[4][4];
#pragma unroll
  for (int i = 0; i < 4; ++i)
#pragma unroll
    for (int j = 0; j < 4; ++j) acc[i][j] = (f32x4){0.f, 0.f, 0.f, 0.f};

  float qv[4], vav[4];
#pragma unroll
  for (int j = 0; j < 4; ++j) {
    int a = wc * 64 + j * 16 + (lane & 15);
    qv[j] = q[b * 128 + a] + bk[a];
    vav[j] = va_g[a];
  }

  for (int k0 = 0; k0 < 512; k0 += 64) {
    __syncthreads();
    {  // stage enc tile: 128 t x 64 k, f32 -> bf16, swizzled
      int r = tid >> 4;          // 0..15
      int k4 = (tid & 15) * 4;   // 0..60
#pragma unroll
      for (int p = 0; p < 8; ++p) {
        int t = r + p * 16;
        const float4 v = *reinterpret_cast<const float4*>(
            &enc[((size_t)(b * 512 + t0 + t)) * 512 + k0 + k4]);
        bf16x4 w;
        w[0] = (__bf16)v.x; w[1] = (__bf16)v.y;
        w[2] = (__bf16)v.z; w[3] = (__bf16)v.w;
        int e = t * 64 + (k4 ^ ((t & 7) << 3));
        *reinterpret_cast<bf16x4*>(&Eb[e]) = w;
      }
      // stage WkT tile: 128 a x 64 k (already bf16), swizzled
      int rw = tid >> 3;         // 0..31
      int kc = (tid & 7) * 8;    // 0..56
#pragma unroll
      for (int p = 0; p < 4; ++p) {
        int a = rw + p * 32;
        uint4 v = *reinterpret_cast<const uint4*>(&WkT[(size_t)a * 512 + k0 + kc]);
        int e = a * 64 + (kc ^ ((a & 7) << 3));
        *reinterpret_cast<uint4*>(&Wb[e]) = v;
      }
    }
    __syncthreads();
#pragma unroll
    for (int kk = 0; kk < 64; kk += 32) {
      bf16x8 af[4], bfr[4];
      int kl = kk + (lane >> 4) * 8;
#pragma unroll
      for (int i = 0; i < 4; ++i) {
        int t = wr * 64 + i * 16 + (lane & 15);
        af[i] = *reinterpret_cast<const bf16x8*>(&Eb[t * 64 + (kl ^ ((t & 7) << 3))]);
      }
#pragma unroll
      for (int j = 0; j < 4; ++j) {
        int a = wc * 64 + j * 16 + (lane & 15);
        bfr[j] = *reinterpret_cast<const bf16x8*>(&Wb[a * 64 + (kl ^ ((a & 7) << 3))]);
      }
#pragma unroll
      for (int i = 0; i < 4; ++i)
#pragma unroll
        for (int j = 0; j < 4; ++j)
          acc[i][j] = __builtin_amdgcn_mfma_f32_16x16x32_bf16(
              af[i], bfr[j], acc[i][j], 0, 0, 0);
    }
  }

  // epilogue: score[t] = sum_a tanh(qv[a] + z[t][a]) * va[a]
#pragma unroll
  for (int i = 0; i < 4; ++i) {
#pragma unroll
    for (int r = 0; r < 4; ++r) {
      float s = 0.0f;
#pragma unroll
      for (int j = 0; j < 4; ++j) s += tanhf(qv[j] + acc[i][j][r]) * vav[j];
      s += __shfl_xor(s, 1, 64);
      s += __shfl_xor(s, 2, 64);
      s += __shfl_xor(s, 4, 64);
      s += __shfl_xor(s, 8, 64);
      if ((lane & 15) == 0)
        red[wr * 64 + i * 16 + (lane >> 4) * 4 + r][wc] = s;
    }
  }
  __syncthreads();
  if (tid < 128)
    score[b * 512 + t0 + tid] = red[tid][0] + red[tid][1] + bscore[0];
}

// ---------------------------------------------------------------------------
// 3) Monotonic-attention scan per batch row (T=512).
// ---------------------------------------------------------------------------
__global__ __launch_bounds__(512) void scan_kernel(
    const float* __restrict__ score, const float* __restrict__ prev_align,
    float* __restrict__ align_out) {
  int b = blockIdx.x, t = threadIdx.x;
  __shared__ float s[512];
  float p = sigmoidf(score[b * 512 + t]);
  float omp = 1.0f - p;
  s[t] = omp;
  __syncthreads();
  for (int off = 1; off < 512; off <<= 1) {
    float v = (t >= off) ? s[t - off] : 1.0f;
    __syncthreads();
    if (t >= off) s[t] *= v;
    __syncthreads();
  }
  float cp_excl = (t == 0) ? 1.0f : s[t - 1];
  __syncthreads();
  float denom = fminf(fmaxf(cp_excl, 1e-10f), 1.0f);
  float r = prev_align[b * 512 + t] / denom;
  s[t] = r;
  __syncthreads();
  for (int off = 1; off < 512; off <<= 1) {
    float v = (t >= off) ? s[t - off] : 0.0f;
    __syncthreads();
    if (t >= off) s[t] += v;
    __syncthreads();
  }
  align_out[b * 512 + t] = p * cp_excl * s[t];
}

// ---------------------------------------------------------------------------
// 4) attentions
// ---------------------------------------------------------------------------
__global__ __launch_bounds__(256) void att_part_kernel(
    const float* __restrict__ align, const float* __restrict__ enc,
    float* __restrict__ ap) {
  int tc = blockIdx.x;
  int vt = blockIdx.y;
  int b = blockIdx.z;
  int tid = threadIdx.x;
  int v = vt * 256 + tid;
  __shared__ float al[64];
  if (tid < 64) al[tid] = align[b * 512 + tc * 64 + tid];
  __syncthreads();
  float acc = 0.0f;
  for (int tt = 0; tt < 64; ++tt) {
    float a = al[tt];
    if (a != 0.0f)
      acc = fmaf(a, enc[((size_t)(b * 512 + tc * 64 + tt)) * 512 + v], acc);
  }
  ap[((size_t)tc * 128 + b) * 512 + v] = acc;
}

__global__ __launch_bounds__(256) void att_comb_kernel(
    const float* __restrict__ ap, float* __restrict__ rnn_in,
    float* __restrict__ proj_in) {
  int b = blockIdx.x;
  int v = blockIdx.y * 256 + threadIdx.x;
  float s = 0.0f;
  for (int tc = 0; tc < 8; ++tc) s += ap[((size_t)tc * 128 + b) * 512 + v];
  rnn_in[(size_t)b * 768 + 256 + v] = s;
  proj_in[(size_t)b * 1536 + 1024 + v] = s;
}

// ---------------------------------------------------------------------------
// 5) LSTM z partials (f32 vector GEMM)
// ---------------------------------------------------------------------------
__global__ __launch_bounds__(256) void zgemm_kernel(
    const float* __restrict__ A0, int K0, const float* __restrict__ W0,
    const float* __restrict__ A1, int K1, const float* __restrict__ W1,
    float* __restrict__ parts) {
  int cb = blockIdx.x;
  int rb = blockIdx.y;
  int zp = blockIdx.z;
  int seg = zp >> 1, kh = zp & 1;
  const float* A = seg ? A1 : A0;
  const float* W = seg ? W1 : W0;
  int K = seg ? K1 : K0;
  int kbeg = kh * (K >> 1), kend = kbeg + (K >> 1);
  int c0 = cb * 64, r0 = rb * 64;
  int tid = threadIdx.x;
  int cg = tid & 15, rg = tid >> 4;
  __shared__ float As[32][68];
  __shared__ float Bs[32][68];
  float acc[4][4] = {};
  for (int k0 = kbeg; k0 < kend; k0 += 32) {
    __syncthreads();
    {
      int kk4 = (tid & 7) * 4;
      int r = tid >> 3;
      for (int pp = 0; pp < 2; ++pp) {
        int rr = r + pp * 32;
        float4 v = *reinterpret_cast<const float4*>(
            &A[(size_t)(r0 + rr) * K + k0 + kk4]);
        As[kk4 + 0][rr] = v.x; As[kk4 + 1][rr] = v.y;
        As[kk4 + 2][rr] = v.z; As[kk4 + 3][rr] = v.w;
      }
      int c4 = (tid & 15) * 4;
      int kk = tid >> 4;
      for (int pp = 0; pp < 2; ++pp) {
        int kkk = kk + pp * 16;
        *reinterpret_cast<float4*>(&Bs[kkk][c4]) =
            *reinterpret_cast<const float4*>(&W[(size_t)(k0 + kkk) * 4096 + c0 + c4]);
      }
    }
    __syncthreads();
    for (int kk = 0; kk < 32; ++kk) {
      float4 a = *reinterpret_cast<const float4*>(&As[kk][rg * 4]);
      float4 w = *reinterpret_cast<const float4*>(&Bs[kk][cg * 4]);
      float aa[4] = {a.x, a.y, a.z, a.w};
      float ww[4] = {w.x, w.y, w.z, w.w};
      for (int r = 0; r < 4; ++r)
        for (int c = 0; c < 4; ++c)
          acc[r][c] = fmaf(aa[r], ww[c], acc[r][c]);
    }
  }
  float* outp = parts + (size_t)zp * (128 * 4096);
  for (int r = 0; r < 4; ++r) {
    float4 v = {acc[r][0], acc[r][1], acc[r][2], acc[r][3]};
    *reinterpret_cast<float4*>(&outp[(size_t)(r0 + rg * 4 + r) * 4096 + c0 + cg * 4]) = v;
  }
}

// ---------------------------------------------------------------------------
// 6) LSTM gates
// ---------------------------------------------------------------------------
__global__ __launch_bounds__(256) void gate_kernel(
    const float* __restrict__ parts, const float* __restrict__ bias,
    const float* __restrict__ c_prev, float* __restrict__ h_out,
    float* __restrict__ c_out, float* __restrict__ h_dst2, int ld2) {
  int idx = blockIdx.x * 256 + threadIdx.x;
  int b = idx >> 10, j = idx & 1023;
  float zv[4];
  for (int g = 0; g < 4; ++g) {
    size_t off = (size_t)b * 4096 + g * 1024 + j;
    float s = bias[g * 1024 + j];
    for (int p = 0; p < 4; ++p) s += parts[(size_t)p * (128 * 4096) + off];
    zv[g] = s;
  }
  float ig = sigmoidf(zv[0]);
  float fg = sigmoidf(zv[1]);
  float gg = tanhf(zv[2]);
  float og = sigmoidf(zv[3]);
  float cn = fg * c_prev[idx] + ig * gg;
  float hn = og * tanhf(cn);
  h_out[idx] = hn;
  c_out[idx] = cn;
  if (h_dst2) h_dst2[(size_t)b * ld2 + j] = hn;
}

// ---------------------------------------------------------------------------
// 7) Projection
// ---------------------------------------------------------------------------
__global__ __launch_bounds__(256) void proj_kernel(
    const float* __restrict__ proj_in, const float* __restrict__ Wp,
    const float* __restrict__ bp, float* __restrict__ mel,
    float* __restrict__ stops) {
  int b = blockIdx.x;
  int tid = threadIdx.x;
  __shared__ float row[1536];
  for (int i = tid; i < 1536; i += 256) row[i] = proj_in[(size_t)b * 1536 + i];
  __syncthreads();
  if (tid < 81) {
    float s = bp[tid];
    for (int m = 0; m < 1536; ++m) s = fmaf(row[m], Wp[m * 81 + tid], s);
    if (tid < 80) mel[b * 80 + tid] = s;
    else stops[b] = s;
  }
}

// ---------------------------------------------------------------------------
extern "C" void kernel_launch(void* const* d_in, const int* in_sizes, int n_in,
                              void* d_out, int out_size, void* d_ws,
                              size_t ws_size, hipStream_t stream) {
  const float* enc  = (const float*)d_in[0];
  const float* mels = (const float*)d_in[1];
  const float* prev = (const float*)d_in[2];
  const float* h1   = (const float*)d_in[3];
  const float* c1   = (const float*)d_in[4];
  const float* h2   = (const float*)d_in[5];
  const float* c2   = (const float*)d_in[6];
  const float* Wp1  = (const float*)d_in[7];
  const float* bp1  = (const float*)d_in[8];
  const float* Wp2  = (const float*)d_in[9];
  const float* bp2  = (const float*)d_in[10];
  const float* Wq   = (const float*)d_in[11];
  const float* Wk   = (const float*)d_in[12];
  const float* bk   = (const float*)d_in[13];
  const float* va   = (const float*)d_in[14];
  const float* bsc  = (const float*)d_in[15];
  const float* Wx1  = (const float*)d_in[16];
  const float* Wh1  = (const float*)d_in[17];
  const float* bl1  = (const float*)d_in[18];
  const float* Wx2  = (const float*)d_in[19];
  const float* Wh2  = (const float*)d_in[20];
  const float* bl2  = (const float*)d_in[21];
  const float* Wpj  = (const float*)d_in[22];
  const float* bpj  = (const float*)d_in[23];

  float* out = (float*)d_out;
  float* mel    = out;            // 128*80
  float* stops  = out + 10240;    // 128
  float* aligno = out + 10368;    // 128*512
  float* h1n    = out + 75904;    // 128*1024
  float* c1n    = out + 206976;
  float* h2n    = out + 338048;
  float* c2n    = out + 469120;

  float* ws = (float*)d_ws;
  float* q_ws   = ws;              // 16384
  float* sc_ws  = ws + 16384;      // 65536
  float* rnn_in = ws + 81920;      // 128*768
  float* prj_in = ws + 180224;     // 128*1536
  float* parts  = ws + 376832;     // 4 * 128*4096
  float* ap_ws  = ws + 2473984;    // 8*128*512
  // WkT (bf16, 128KB) aliases the head of `parts` — dead before zgemm runs.
  __bf16* WkT = (__bf16*)parts;

  hipLaunchKernelGGL(prenet_kernel, dim3(128), dim3(256), 0, stream,
                     mels, Wp1, bp1, Wp2, bp2, Wq, rnn_in, q_ws);
  hipLaunchKernelGGL(wkt_prep_kernel, dim3(64), dim3(256), 0, stream,
                     Wk, WkT);
  hipLaunchKernelGGL(score_mfma_kernel, dim3(4, 128), dim3(256), 0, stream,
                     enc, WkT, bk, q_ws, va, bsc, sc_ws);
  hipLaunchKernelGGL(scan_kernel, dim3(128), dim3(512), 0, stream,
                     sc_ws, prev, aligno);
  hipLaunchKernelGGL(att_part_kernel, dim3(8, 2, 128), dim3(256), 0, stream,
                     aligno, enc, ap_ws);
  hipLaunchKernelGGL(att_comb_kernel, dim3(128, 2), dim3(256), 0, stream,
                     ap_ws, rnn_in, prj_in);
  hipLaunchKernelGGL(zgemm_kernel, dim3(64, 2, 4), dim3(256), 0, stream,
                     rnn_in, 768, Wx1, h1, 1024, Wh1, parts);
  hipLaunchKernelGGL(gate_kernel, dim3(512), dim3(256), 0, stream,
                     parts, bl1, c1, h1n, c1n, (float*)nullptr, 0);
  hipLaunchKernelGGL(zgemm_kernel, dim3(64, 2, 4), dim3(256), 0, stream,
                     h1n, 1024, Wx2, h2, 1024, Wh2, parts);
  hipLaunchKernelGGL(gate_kernel, dim3(512), dim3(256), 0, stream,
                     parts, bl2, c2, h2n, c2n, prj_in, 1536);
  hipLaunchKernelGGL(proj_kernel, dim3(128), dim3(256), 0, stream,
                     prj_in, Wpj, bpj, mel, stops);
}

// Round 3
// 157.420 us; speedup vs baseline: 1.8402x; 1.2446x over previous
//
#include <hip/hip_runtime.h>
#include <math.h>

typedef float f32x4 __attribute__((ext_vector_type(4)));
typedef __bf16 bf16x8 __attribute__((ext_vector_type(8)));
typedef __bf16 bf16x4 __attribute__((ext_vector_type(4)));

// ---------------------------------------------------------------------------
// JAX threefry2x32 (exact port) + dropout mask replication.
// ---------------------------------------------------------------------------
#define PARTITIONABLE 1

__device__ __forceinline__ void threefry2x32(unsigned k0, unsigned k1,
                                             unsigned c0, unsigned c1,
                                             unsigned &o0, unsigned &o1) {
  unsigned ks2 = k0 ^ k1 ^ 0x1BD11BDAu;
  unsigned x0 = c0 + k0, x1 = c1 + k1;
#define ROTL(v, n) (((v) << (n)) | ((v) >> (32 - (n))))
#define R4(a, b, c, d)                                   \
  { x0 += x1; x1 = ROTL(x1, a); x1 ^= x0;                \
    x0 += x1; x1 = ROTL(x1, b); x1 ^= x0;                \
    x0 += x1; x1 = ROTL(x1, c); x1 ^= x0;                \
    x0 += x1; x1 = ROTL(x1, d); x1 ^= x0; }
  R4(13, 15, 26, 6);  x0 += k1;  x1 += ks2 + 1u;
  R4(17, 29, 16, 24); x0 += ks2; x1 += k0 + 2u;
  R4(13, 15, 26, 6);  x0 += k0;  x1 += k1 + 3u;
  R4(17, 29, 16, 24); x0 += k1;  x1 += ks2 + 4u;
  R4(13, 15, 26, 6);  x0 += ks2; x1 += k0 + 5u;
  o0 = x0; o1 = x1;
#undef R4
#undef ROTL
}

__device__ __forceinline__ float dropout_scale(int layer, unsigned i) {
#if PARTITIONABLE
  unsigned d0, d1, y0, y1;
  threefry2x32(0u, 7u, 0u, (unsigned)layer, d0, d1);
  threefry2x32(d0, d1, 0u, i, y0, y1);
  unsigned bits = y0 ^ y1;
#else
  unsigned a0, b0, a1, b1v, y0, y1;
  threefry2x32(0u, 7u, 0u, 2u, a0, b0);
  threefry2x32(0u, 7u, 1u, 3u, a1, b1v);
  unsigned k0 = (layer == 0) ? a0 : b0;
  unsigned k1 = (layer == 0) ? a1 : b1v;
  const unsigned half = 16384u;
  unsigned lane = (i < half) ? 0u : 1u;
  unsigned j = lane ? (i - half) : i;
  threefry2x32(k0, k1, j, j + half, y0, y1);
  unsigned bits = lane ? y1 : y0;
#endif
  return (bits & 0x80000000u) ? 0.0f : 2.0f;
}

__device__ __forceinline__ float sigmoidf(float x) {
  return 1.0f / (1.0f + expf(-x));
}

// ---------------------------------------------------------------------------
// 1) Prenet
// ---------------------------------------------------------------------------
__global__ __launch_bounds__(256) void prenet_kernel(
    const float* __restrict__ mels, const float* __restrict__ W1,
    const float* __restrict__ b1, const float* __restrict__ W2,
    const float* __restrict__ b2, const float* __restrict__ Wq,
    float* __restrict__ rnn_in, float* __restrict__ q_out) {
  int b = blockIdx.x;
  int j = threadIdx.x;
  __shared__ float mel_s[80];
  __shared__ float x1_s[256];
  __shared__ float x2_s[256];
  if (j < 80) mel_s[j] = mels[b * 80 + j];
  __syncthreads();
  float s = b1[j];
  for (int m = 0; m < 80; ++m) s = fmaf(mel_s[m], W1[m * 256 + j], s);
  s = fmaxf(s, 0.0f) * dropout_scale(0, (unsigned)(b * 256 + j));
  x1_s[j] = s;
  __syncthreads();
  float s2 = b2[j];
  for (int m = 0; m < 256; ++m) s2 = fmaf(x1_s[m], W2[m * 256 + j], s2);
  s2 = fmaxf(s2, 0.0f) * dropout_scale(1, (unsigned)(b * 256 + j));
  x2_s[j] = s2;
  rnn_in[(size_t)b * 768 + j] = s2;
  __syncthreads();
  if (j < 128) {
    float sq = 0.0f;
    for (int m = 0; m < 256; ++m) sq = fmaf(x2_s[m], Wq[m * 128 + j], sq);
    q_out[b * 128 + j] = sq;
  }
}

// ---------------------------------------------------------------------------
// 1b) Wk -> WkT (transposed, bf16)
// ---------------------------------------------------------------------------
__global__ __launch_bounds__(256) void wkt_prep_kernel(
    const float* __restrict__ Wk, __bf16* __restrict__ WkT) {
  int gid = blockIdx.x * 256 + threadIdx.x;
  int a = gid & 127;
  int k4 = (gid >> 7) * 4;
  bf16x4 w;
  for (int i = 0; i < 4; ++i) w[i] = (__bf16)Wk[(size_t)(k4 + i) * 128 + a];
  *reinterpret_cast<bf16x4*>(&WkT[(size_t)a * 512 + k4]) = w;
}

// ---------------------------------------------------------------------------
// 2) score via MFMA
// ---------------------------------------------------------------------------
__global__ __launch_bounds__(256) void score_mfma_kernel(
    const float* __restrict__ enc, const __bf16* __restrict__ WkT,
    const float* __restrict__ bk, const float* __restrict__ q,
    const float* __restrict__ va_g, const float* __restrict__ bscore,
    float* __restrict__ score) {
  int b = blockIdx.y;
  int t0 = blockIdx.x * 128;
  int tid = threadIdx.x;
  int lane = tid & 63, wid = tid >> 6;
  int wr = wid >> 1, wc = wid & 1;
  __shared__ __align__(16) __bf16 Eb[128 * 64];
  __shared__ __align__(16) __bf16 Wb[128 * 64];
  __shared__ float red[128][4];

  f32x4 acc[4][4];
#pragma unroll
  for (int i = 0; i < 4; ++i)
#pragma unroll
    for (int j = 0; j < 4; ++j) acc[i][j] = (f32x4){0.f, 0.f, 0.f, 0.f};

  float qv[4], vav[4];
#pragma unroll
  for (int j = 0; j < 4; ++j) {
    int a = wc * 64 + j * 16 + (lane & 15);
    qv[j] = q[b * 128 + a] + bk[a];
    vav[j] = va_g[a];
  }

  for (int k0 = 0; k0 < 512; k0 += 64) {
    __syncthreads();
    {
      int r = tid >> 4;
      int k4 = (tid & 15) * 4;
#pragma unroll
      for (int p = 0; p < 8; ++p) {
        int t = r + p * 16;
        const float4 v = *reinterpret_cast<const float4*>(
            &enc[((size_t)(b * 512 + t0 + t)) * 512 + k0 + k4]);
        bf16x4 w;
        w[0] = (__bf16)v.x; w[1] = (__bf16)v.y;
        w[2] = (__bf16)v.z; w[3] = (__bf16)v.w;
        int e = t * 64 + (k4 ^ ((t & 7) << 3));
        *reinterpret_cast<bf16x4*>(&Eb[e]) = w;
      }
      int rw = tid >> 3;
      int kc = (tid & 7) * 8;
#pragma unroll
      for (int p = 0; p < 4; ++p) {
        int a = rw + p * 32;
        uint4 v = *reinterpret_cast<const uint4*>(&WkT[(size_t)a * 512 + k0 + kc]);
        int e = a * 64 + (kc ^ ((a & 7) << 3));
        *reinterpret_cast<uint4*>(&Wb[e]) = v;
      }
    }
    __syncthreads();
#pragma unroll
    for (int kk = 0; kk < 64; kk += 32) {
      bf16x8 af[4], bfr[4];
      int kl = kk + (lane >> 4) * 8;
#pragma unroll
      for (int i = 0; i < 4; ++i) {
        int t = wr * 64 + i * 16 + (lane & 15);
        af[i] = *reinterpret_cast<const bf16x8*>(&Eb[t * 64 + (kl ^ ((t & 7) << 3))]);
      }
#pragma unroll
      for (int j = 0; j < 4; ++j) {
        int a = wc * 64 + j * 16 + (lane & 15);
        bfr[j] = *reinterpret_cast<const bf16x8*>(&Wb[a * 64 + (kl ^ ((a & 7) << 3))]);
      }
#pragma unroll
      for (int i = 0; i < 4; ++i)
#pragma unroll
        for (int j = 0; j < 4; ++j)
          acc[i][j] = __builtin_amdgcn_mfma_f32_16x16x32_bf16(
              af[i], bfr[j], acc[i][j], 0, 0, 0);
    }
  }

#pragma unroll
  for (int i = 0; i < 4; ++i) {
#pragma unroll
    for (int r = 0; r < 4; ++r) {
      float s = 0.0f;
#pragma unroll
      for (int j = 0; j < 4; ++j) s += tanhf(qv[j] + acc[i][j][r]) * vav[j];
      s += __shfl_xor(s, 1, 64);
      s += __shfl_xor(s, 2, 64);
      s += __shfl_xor(s, 4, 64);
      s += __shfl_xor(s, 8, 64);
      if ((lane & 15) == 0)
        red[wr * 64 + i * 16 + (lane >> 4) * 4 + r][wc] = s;
    }
  }
  __syncthreads();
  if (tid < 128)
    score[b * 512 + t0 + tid] = red[tid][0] + red[tid][1] + bscore[0];
}

// ---------------------------------------------------------------------------
// 3) Monotonic-attention scan
// ---------------------------------------------------------------------------
__global__ __launch_bounds__(512) void scan_kernel(
    const float* __restrict__ score, const float* __restrict__ prev_align,
    float* __restrict__ align_out) {
  int b = blockIdx.x, t = threadIdx.x;
  __shared__ float s[512];
  float p = sigmoidf(score[b * 512 + t]);
  float omp = 1.0f - p;
  s[t] = omp;
  __syncthreads();
  for (int off = 1; off < 512; off <<= 1) {
    float v = (t >= off) ? s[t - off] : 1.0f;
    __syncthreads();
    if (t >= off) s[t] *= v;
    __syncthreads();
  }
  float cp_excl = (t == 0) ? 1.0f : s[t - 1];
  __syncthreads();
  float denom = fminf(fmaxf(cp_excl, 1e-10f), 1.0f);
  float r = prev_align[b * 512 + t] / denom;
  s[t] = r;
  __syncthreads();
  for (int off = 1; off < 512; off <<= 1) {
    float v = (t >= off) ? s[t - off] : 0.0f;
    __syncthreads();
    if (t >= off) s[t] += v;
    __syncthreads();
  }
  align_out[b * 512 + t] = p * cp_excl * s[t];
}

// ---------------------------------------------------------------------------
// 4) attentions
// ---------------------------------------------------------------------------
__global__ __launch_bounds__(256) void att_part_kernel(
    const float* __restrict__ align, const float* __restrict__ enc,
    float* __restrict__ ap) {
  int tc = blockIdx.x;
  int vt = blockIdx.y;
  int b = blockIdx.z;
  int tid = threadIdx.x;
  int v = vt * 256 + tid;
  __shared__ float al[64];
  if (tid < 64) al[tid] = align[b * 512 + tc * 64 + tid];
  __syncthreads();
  float acc = 0.0f;
  for (int tt = 0; tt < 64; ++tt) {
    float a = al[tt];
    if (a != 0.0f)
      acc = fmaf(a, enc[((size_t)(b * 512 + tc * 64 + tt)) * 512 + v], acc);
  }
  ap[((size_t)tc * 128 + b) * 512 + v] = acc;
}

__global__ __launch_bounds__(256) void att_comb_kernel(
    const float* __restrict__ ap, float* __restrict__ rnn_in,
    float* __restrict__ proj_in) {
  int b = blockIdx.x;
  int v = blockIdx.y * 256 + threadIdx.x;
  float s = 0.0f;
  for (int tc = 0; tc < 8; ++tc) s += ap[((size_t)tc * 128 + b) * 512 + v];
  rnn_in[(size_t)b * 768 + 256 + v] = s;
  proj_in[(size_t)b * 1536 + 1024 + v] = s;
}

// ---------------------------------------------------------------------------
// 5) LSTM z partials via MFMA. Block = 128 rows x 128 cols, K-chunk.
//    A staged to LDS (f32->bf16, XOR-swizzled). W (B operand) fragments loaded
//    DIRECTLY from global f32 (4x64B coalesced segments per dword load, every
//    byte used exactly once) and converted in registers — no W transpose.
//    Grid: (32 col-blocks, 8 zp) ; zp: seg = zp>>2, K-quarter = zp&3.
// ---------------------------------------------------------------------------
__global__ __launch_bounds__(256) void zgemm_mfma_kernel(
    const float* __restrict__ A0, int K0, const float* __restrict__ W0,
    const float* __restrict__ A1, int K1, const float* __restrict__ W1,
    float* __restrict__ parts) {
  int cb = blockIdx.x;   // 0..31
  int zp = blockIdx.y;   // 0..7
  int seg = zp >> 2, kq = zp & 3;
  const float* A = seg ? A1 : A0;
  const float* W = seg ? W1 : W0;
  int K = seg ? K1 : K0;
  int kc = K >> 2;                 // 192 or 256 (multiple of 64)
  int kbeg = kq * kc, kend = kbeg + kc;
  int tid = threadIdx.x;
  int lane = tid & 63, wid = tid >> 6;
  int wr = wid >> 1, wc = wid & 1;
  __shared__ __align__(16) __bf16 Ab[128 * 64];

  f32x4 acc[4][4];
#pragma unroll
  for (int i = 0; i < 4; ++i)
#pragma unroll
    for (int j = 0; j < 4; ++j) acc[i][j] = (f32x4){0.f, 0.f, 0.f, 0.f};

  int n_base = cb * 128 + wc * 64 + (lane & 15);
  int koct = (lane >> 4) * 8;

  for (int k0 = kbeg; k0 < kend; k0 += 64) {
    __syncthreads();
    {  // stage A: 128 rows x 64 k, f32->bf16, swizzled
      int r = tid >> 4;
      int k4 = (tid & 15) * 4;
#pragma unroll
      for (int p = 0; p < 8; ++p) {
        int row = r + p * 16;
        const float4 v = *reinterpret_cast<const float4*>(
            &A[(size_t)row * K + k0 + k4]);
        bf16x4 w;
        w[0] = (__bf16)v.x; w[1] = (__bf16)v.y;
        w[2] = (__bf16)v.z; w[3] = (__bf16)v.w;
        *reinterpret_cast<bf16x4*>(&Ab[row * 64 + (k4 ^ ((row & 7) << 3))]) = w;
      }
    }
    __syncthreads();
#pragma unroll
    for (int kk = 0; kk < 64; kk += 32) {
      bf16x8 af[4];
      int kl = kk + koct;
#pragma unroll
      for (int i = 0; i < 4; ++i) {
        int t = wr * 64 + i * 16 + (lane & 15);
        af[i] = *reinterpret_cast<const bf16x8*>(&Ab[t * 64 + (kl ^ ((t & 7) << 3))]);
      }
      bf16x8 bfr[4];
      const float* wp = W + (size_t)(k0 + kk + koct) * 4096 + n_base;
#pragma unroll
      for (int jf = 0; jf < 4; ++jf) {
        const float* wq = wp + jf * 16;
        bf16x8 bv;
#pragma unroll
        for (int j = 0; j < 8; ++j) bv[j] = (__bf16)wq[(size_t)j * 4096];
        bfr[jf] = bv;
      }
#pragma unroll
      for (int i = 0; i < 4; ++i)
#pragma unroll
        for (int jf = 0; jf < 4; ++jf)
          acc[i][jf] = __builtin_amdgcn_mfma_f32_16x16x32_bf16(
              af[i], bfr[jf], acc[i][jf], 0, 0, 0);
    }
  }

  float* outp = parts + (size_t)zp * (128 * 4096);
#pragma unroll
  for (int i = 0; i < 4; ++i) {
#pragma unroll
    for (int jf = 0; jf < 4; ++jf) {
#pragma unroll
      for (int r = 0; r < 4; ++r) {
        int row = wr * 64 + i * 16 + ((lane >> 4) << 2) + r;
        int col = cb * 128 + wc * 64 + jf * 16 + (lane & 15);
        outp[(size_t)row * 4096 + col] = acc[i][jf][r];
      }
    }
  }
}

// ---------------------------------------------------------------------------
// 6) LSTM gates: z = sum of 8 parts + bias
// ---------------------------------------------------------------------------
__global__ __launch_bounds__(256) void gate_kernel(
    const float* __restrict__ parts, const float* __restrict__ bias,
    const float* __restrict__ c_prev, float* __restrict__ h_out,
    float* __restrict__ c_out, float* __restrict__ h_dst2, int ld2) {
  int idx = blockIdx.x * 256 + threadIdx.x;
  int b = idx >> 10, j = idx & 1023;
  float zv[4];
  for (int g = 0; g < 4; ++g) {
    size_t off = (size_t)b * 4096 + g * 1024 + j;
    float s = bias[g * 1024 + j];
    for (int p = 0; p < 8; ++p) s += parts[(size_t)p * (128 * 4096) + off];
    zv[g] = s;
  }
  float ig = sigmoidf(zv[0]);
  float fg = sigmoidf(zv[1]);
  float gg = tanhf(zv[2]);
  float og = sigmoidf(zv[3]);
  float cn = fg * c_prev[idx] + ig * gg;
  float hn = og * tanhf(cn);
  h_out[idx] = hn;
  c_out[idx] = cn;
  if (h_dst2) h_dst2[(size_t)b * ld2 + j] = hn;
}

// ---------------------------------------------------------------------------
// 7) Projection
// ---------------------------------------------------------------------------
__global__ __launch_bounds__(256) void proj_kernel(
    const float* __restrict__ proj_in, const float* __restrict__ Wp,
    const float* __restrict__ bp, float* __restrict__ mel,
    float* __restrict__ stops) {
  int b = blockIdx.x;
  int tid = threadIdx.x;
  __shared__ float row[1536];
  for (int i = tid; i < 1536; i += 256) row[i] = proj_in[(size_t)b * 1536 + i];
  __syncthreads();
  if (tid < 81) {
    float s = bp[tid];
    for (int m = 0; m < 1536; ++m) s = fmaf(row[m], Wp[m * 81 + tid], s);
    if (tid < 80) mel[b * 80 + tid] = s;
    else stops[b] = s;
  }
}

// ---------------------------------------------------------------------------
extern "C" void kernel_launch(void* const* d_in, const int* in_sizes, int n_in,
                              void* d_out, int out_size, void* d_ws,
                              size_t ws_size, hipStream_t stream) {
  const float* enc  = (const float*)d_in[0];
  const float* mels = (const float*)d_in[1];
  const float* prev = (const float*)d_in[2];
  const float* h1   = (const float*)d_in[3];
  const float* c1   = (const float*)d_in[4];
  const float* h2   = (const float*)d_in[5];
  const float* c2   = (const float*)d_in[6];
  const float* Wp1  = (const float*)d_in[7];
  const float* bp1  = (const float*)d_in[8];
  const float* Wp2  = (const float*)d_in[9];
  const float* bp2  = (const float*)d_in[10];
  const float* Wq   = (const float*)d_in[11];
  const float* Wk   = (const float*)d_in[12];
  const float* bk   = (const float*)d_in[13];
  const float* va   = (const float*)d_in[14];
  const float* bsc  = (const float*)d_in[15];
  const float* Wx1  = (const float*)d_in[16];
  const float* Wh1  = (const float*)d_in[17];
  const float* bl1  = (const float*)d_in[18];
  const float* Wx2  = (const float*)d_in[19];
  const float* Wh2  = (const float*)d_in[20];
  const float* bl2  = (const float*)d_in[21];
  const float* Wpj  = (const float*)d_in[22];
  const float* bpj  = (const float*)d_in[23];

  float* out = (float*)d_out;
  float* mel    = out;            // 128*80
  float* stops  = out + 10240;    // 128
  float* aligno = out + 10368;    // 128*512
  float* h1n    = out + 75904;    // 128*1024
  float* c1n    = out + 206976;
  float* h2n    = out + 338048;
  float* c2n    = out + 469120;

  float* ws = (float*)d_ws;
  float* q_ws   = ws;              // 16384
  float* sc_ws  = ws + 16384;      // 65536
  float* rnn_in = ws + 81920;      // 128*768
  float* prj_in = ws + 180224;     // 128*1536
  float* parts  = ws + 376832;     // 8 * 128*4096 = 4,194,304
  float* ap_ws  = ws + 4571136;    // 8*128*512 (end 5,095,424 floats ~20MB)
  // WkT (bf16, 128KB) aliases the head of `parts` — dead before zgemm runs.
  __bf16* WkT = (__bf16*)parts;

  hipLaunchKernelGGL(prenet_kernel, dim3(128), dim3(256), 0, stream,
                     mels, Wp1, bp1, Wp2, bp2, Wq, rnn_in, q_ws);
  hipLaunchKernelGGL(wkt_prep_kernel, dim3(64), dim3(256), 0, stream,
                     Wk, WkT);
  hipLaunchKernelGGL(score_mfma_kernel, dim3(4, 128), dim3(256), 0, stream,
                     enc, WkT, bk, q_ws, va, bsc, sc_ws);
  hipLaunchKernelGGL(scan_kernel, dim3(128), dim3(512), 0, stream,
                     sc_ws, prev, aligno);
  hipLaunchKernelGGL(att_part_kernel, dim3(8, 2, 128), dim3(256), 0, stream,
                     aligno, enc, ap_ws);
  hipLaunchKernelGGL(att_comb_kernel, dim3(128, 2), dim3(256), 0, stream,
                     ap_ws, rnn_in, prj_in);
  hipLaunchKernelGGL(zgemm_mfma_kernel, dim3(32, 8), dim3(256), 0, stream,
                     rnn_in, 768, Wx1, h1, 1024, Wh1, parts);
  hipLaunchKernelGGL(gate_kernel, dim3(512), dim3(256), 0, stream,
                     parts, bl1, c1, h1n, c1n, (float*)nullptr, 0);
  hipLaunchKernelGGL(zgemm_mfma_kernel, dim3(32, 8), dim3(256), 0, stream,
                     h1n, 1024, Wx2, h2, 1024, Wh2, parts);
  hipLaunchKernelGGL(gate_kernel, dim3(512), dim3(256), 0, stream,
                     parts, bl2, c2, h2n, c2n, prj_in, 1536);
  hipLaunchKernelGGL(proj_kernel, dim3(128), dim3(256), 0, stream,
                     prj_in, Wpj, bpj, mel, stops);
}